// Round 4
// baseline (74.434 us; speedup 1.0000x reference)
//
#include <hip/hip_runtime.h>

#define DIM 4096
#define NB 128
// padded float2 strides in LDS state buffer: addr = i0*S0 + i1*S1 + i2
#define S1 17
#define S0 274

// One dispatch. Block = (batch b, i1-quarter qq): 512 blocks x 256 threads.
// Passes: U1 (in-place, thread owns fiber), U2 (-> B), U0 (-> global).
__global__ __launch_bounds__(256)
void ulayer_fused(const float* __restrict__ thetas,
                  const float* __restrict__ evecs,
                  const float* __restrict__ evals,
                  const float* __restrict__ sre,
                  const float* __restrict__ sim,
                  float* __restrict__ out)
{
    __shared__ float  sV[256];
    __shared__ float  sC[48], sS[48];
    __shared__ float2 sG[3][16][16];   // gates
    __shared__ float2 st[16 * S0];     // state, padded [i0][i1][i2]   (35 KB)
    __shared__ float2 B[4][16][17];    // U2 out: [i1loc][i2][i0]      (8.7 KB)

    const int t  = threadIdx.x;
    const int b  = blockIdx.x >> 2;
    const int qq = blockIdx.x & 3;

    // ---- coalesced global loads first; latency hides under staging ----
    const float4* __restrict__ vre = (const float4*)(sre + (size_t)b * DIM);
    const float4* __restrict__ vim = (const float4*)(sim + (size_t)b * DIM);
    float4 lre[4], lim[4];
#pragma unroll
    for (int it = 0; it < 4; ++it) {
        lre[it] = vre[t + 256 * it];
        lim[it] = vim[t + 256 * it];
    }

    // ---- stage V and per-(gate,eig) trig (HW sincos path) ----
    sV[t] = evecs[t];
    if (t < 48) {
        const int g = t >> 4, k = t & 15;
        float sn, cs;
        __sincosf(thetas[g] * evals[k], &sn, &cs);
        sC[t] = cs;
        sS[t] = sn;
    }

    // ---- scatter state into padded LDS ----
#pragma unroll
    for (int it = 0; it < 4; ++it) {
        const int e0 = (t + 256 * it) << 2;      // element index, multiple of 4
        const int i0 = e0 >> 8;
        const int r  = e0 & 255;                 // i1*16 + i2
        const int base = i0 * S0 + (r >> 4) * S1 + (r & 15);
        const float* pr = (const float*)&lre[it];
        const float* pi = (const float*)&lim[it];
#pragma unroll
        for (int q = 0; q < 4; ++q)
            st[base + q] = make_float2(pr[q], pi[q]);
    }
    __syncthreads();

    // ---- build gates: U[i,j] = sum_k V[i,k]V[j,k](cos - i sin) ----
#pragma unroll
    for (int rep = 0; rep < 3; ++rep) {
        const int e = t + (rep << 8);
        const int g = e >> 8;
        const int i = (e >> 4) & 15;
        const int j = e & 15;
        float gr = 0.f, gi = 0.f;
#pragma unroll
        for (int k = 0; k < 16; ++k) {
            const float vv = sV[i * 16 + k] * sV[j * 16 + k];
            gr = fmaf(vv,  sC[(g << 4) + k], gr);
            gi = fmaf(vv, -sS[(g << 4) + k], gi);
        }
        sG[g][i][j] = make_float2(gr, gi);
    }
    __syncthreads();

    // ---- U1 (axis i1), in place: thread owns fiber (i0 = t>>4, i2 = t&15);
    //      reads all 16 rows, writes only its quarter's 4 rows. No other
    //      thread touches this fiber => no intra-pass barrier needed.
    {
        const int i0 = t >> 4;
        const int i2 = t & 15;
        const int fb = i0 * S0 + i2;
        float2 x[16];
#pragma unroll
        for (int j = 0; j < 16; ++j) x[j] = st[fb + j * S1];
#pragma unroll
        for (int l = 0; l < 4; ++l) {
            const int row = qq * 4 + l;          // block-uniform -> broadcast
            float ar = 0.f, ai = 0.f;
#pragma unroll
            for (int j = 0; j < 16; ++j) {
                const float2 g = sG[1][row][j];
                ar = fmaf(g.x,  x[j].x, ar);
                ar = fmaf(-g.y, x[j].y, ar);
                ai = fmaf(g.x,  x[j].y, ai);
                ai = fmaf(g.y,  x[j].x, ai);
            }
            st[fb + row * S1] = make_float2(ar, ai);
        }
    }
    __syncthreads();

    // ---- U2 (axis i2): wave-uniform output group ig = t>>6 ----
    {
        const int ig  = t >> 6;
        const int fid = t & 63;
        const int fi0 = fid >> 2;
        const int fl  = fid & 3;
        const int fb  = fi0 * S0 + (qq * 4 + fl) * S1;
        float2 x2[16];
#pragma unroll
        for (int j = 0; j < 16; ++j) x2[j] = st[fb + j];   // consecutive float2
#pragma unroll
        for (int q = 0; q < 4; ++q) {
            const int r = ig * 4 + q;            // wave-uniform gate row
            float ar = 0.f, ai = 0.f;
#pragma unroll
            for (int j = 0; j < 16; ++j) {
                const float2 g = sG[2][r][j];
                ar = fmaf(g.x,  x2[j].x, ar);
                ar = fmaf(-g.y, x2[j].y, ar);
                ai = fmaf(g.x,  x2[j].y, ai);
                ai = fmaf(g.y,  x2[j].x, ai);
            }
            B[fl][r][fi0] = make_float2(ar, ai);
        }
    }
    __syncthreads();

    // ---- U0 (axis i0) + coalesced store ----
    {
        const int rg  = t >> 6;                  // wave-uniform output group
        const int fl6 = t & 63;
        const int l   = fl6 >> 4;
        const int i2f = fl6 & 15;
        float2 x0[16];
#pragma unroll
        for (int j = 0; j < 16; ++j) x0[j] = B[l][i2f][j];

        float* __restrict__ ore = out + (size_t)b * DIM;
        float* __restrict__ oim = out + (size_t)NB * DIM + (size_t)b * DIM;
#pragma unroll
        for (int r = 0; r < 4; ++r) {
            const int ro = rg * 4 + r;
            float ar = 0.f, ai = 0.f;
#pragma unroll
            for (int j = 0; j < 16; ++j) {
                const float2 g = sG[0][ro][j];
                ar = fmaf(g.x,  x0[j].x, ar);
                ar = fmaf(-g.y, x0[j].y, ar);
                ai = fmaf(g.x,  x0[j].y, ai);
                ai = fmaf(g.y,  x0[j].x, ai);
            }
            const int od = ro * 256 + (qq * 4 + l) * 16 + i2f;  // 64-float runs/wave
            ore[od] = ar;
            oim[od] = ai;
        }
    }
}

extern "C" void kernel_launch(void* const* d_in, const int* in_sizes, int n_in,
                              void* d_out, int out_size, void* d_ws, size_t ws_size,
                              hipStream_t stream) {
    const float* thetas = (const float*)d_in[0];
    const float* evecs  = (const float*)d_in[1];
    const float* evals  = (const float*)d_in[2];
    const float* sre    = (const float*)d_in[3];
    const float* sim    = (const float*)d_in[4];
    float* outp = (float*)d_out;
    ulayer_fused<<<NB * 4, 256, 0, stream>>>(thetas, evecs, evals, sre, sim, outp);
}